// Round 8
// baseline (333.935 us; speedup 1.0000x reference)
//
#include <hip/hip_runtime.h>
#include <hip/hip_bf16.h>

#define EMB 128

typedef __attribute__((ext_vector_type(8))) short short8;   // 8 bf16 (4 VGPRs)
typedef __attribute__((ext_vector_type(4))) float floatx4;  // MFMA C/D

// 26 valid (ok, di, ol) message combos: deltas = {1,2,-1,-2}, ol = ok+delta in [0,8)
static constexpr int OKv[26] = {0,0,1,1,1,2,2,2,2,3,3,3,3,4,4,4,4,5,5,5,5,6,6,6,7,7};
static constexpr int DIv[26] = {0,1,0,1,2,0,1,2,3,0,1,2,3,0,1,2,3,0,1,2,3,0,2,3,2,3};
static constexpr int OLv[26] = {1,2,2,3,0,3,4,1,0,4,5,2,1,5,6,3,2,6,7,4,3,7,5,4,6,5};

__device__ __forceinline__ float4 ld4(const float* p) { return *(const float4*)p; }

// round-to-nearest-even bf16 bits of x, kept in the TOP 16 bits (low 16 zero)
__device__ __forceinline__ unsigned bf16_rne_hi(float x) {
  unsigned u = __float_as_uint(x);
  return (u + 0x7FFFu + ((u >> 16) & 1u)) & 0xFFFF0000u;
}
__device__ __forceinline__ float bf16hi_f(float x) {
  return __uint_as_float(bf16_rne_hi(x));
}
// HW packed cvt: a -> low 16, b -> high 16 (v_cvt_pk_bf16_f32 on gfx950)
__device__ __forceinline__ unsigned cvt_pk_bf16(float a, float b) {
  __hip_bfloat162 h = __float22bfloat162_rn(make_float2(a, b));
  unsigned r; __builtin_memcpy(&r, &h, 4); return r;
}

union FragU { unsigned u[4]; uint4 q; short8 v; };

// Fused prep: blocks 0..31 = lin32 rows (+ block 0 also writes out[g]=b_pred),
// blocks 32..111 = w_conv -> B-fragment hi/lo pre-pack (R4-verified layout).
__global__ void prep_kernel(const float* __restrict__ emb_x,
                            const float* __restrict__ w_ti,
                            const float* __restrict__ b_ti,
                            const float* __restrict__ w_conv,
                            const float* __restrict__ b_pred,
                            float* __restrict__ lin32,
                            uint4* __restrict__ wfrag,
                            float* __restrict__ out) {
  const int b = blockIdx.x, tid = threadIdx.x;
  if (b < 32) {
    if (tid < EMB) {
      const int e = tid;
      const float* xr = emb_x + b * EMB;
      float a0 = b_ti[e], a1 = 0.f, a2 = 0.f, a3 = 0.f;
      #pragma unroll 4
      for (int f = 0; f < EMB; f += 4) {
        a0 = fmaf(xr[f + 0], w_ti[(f + 0) * EMB + e], a0);
        a1 = fmaf(xr[f + 1], w_ti[(f + 1) * EMB + e], a1);
        a2 = fmaf(xr[f + 2], w_ti[(f + 2) * EMB + e], a2);
        a3 = fmaf(xr[f + 3], w_ti[(f + 3) * EMB + e], a3);
      }
      lin32[b * EMB + e] = (a0 + a1) + (a2 + a3);
    } else if (b == 0 && tid >= 128 && tid < 192) {
      out[tid - 128] = b_pred[0];
    }
  } else {
    const int id   = (b - 32) * 256 + tid;   // 320 frags * 64 lanes = 20480
    const int lane = id & 63;
    const int f    = id >> 6;
    const int pass = f & 1;           // 0 = hi, 1 = lo
    const int u    = (f >> 1) & 7;    // N-tile
    const int t    = (f >> 4) & 3;    // K-tile
    const int l    = f >> 6;          // layer
    const int q    = lane >> 4, n = lane & 15;
    unsigned w[4] = {0u, 0u, 0u, 0u};
    #pragma unroll
    for (int j = 0; j < 8; ++j) {
      const int ff = t * 32 + q * 8 + j;
      const int c  = u * 16 + n;
      float val = w_conv[l * (EMB * EMB) + ff * EMB + c];
      if (pass) val = val - bf16hi_f(val);
      const unsigned bb = bf16_rne_hi(val);
      w[j >> 1] |= (j & 1) ? bb : (bb >> 16);
    }
    wfrag[id] = make_uint4(w[0], w[1], w[2], w[3]);
  }
}

// Block = root node i. X lives in MFMA C-layout REGISTERS for all 5 layers:
// M-row permutation row(pair,k) = ((pair&1)+2*(k>>2))*16 + (pair>>1)*4 + (k&3)
// makes lane (m16,q2) hold pairs {2q2, 2q2+1} x all 8 k at channels
// ch_v = wv*32 + v*16 + m16. Message pass is lane-local; only the A-fragment
// transpose goes through LDS (fp32, stride-132 pad: writes 2-way free, reads
// at 8-sweep floor), converted to bf16 hi/lo in registers. 2 barriers/layer
// (was 4). No occupancy attribute (R1/R6: forcing a budget -> giant spills).
__global__ __launch_bounds__(256)
void i2gnn_mfma(
    const int* __restrict__ x,
    const int* __restrict__ edge_attr,
    const int* __restrict__ tuplefeat,
    const float* __restrict__ emb_x,
    const float* __restrict__ emb_tf,
    const float* __restrict__ emb_ea,
    const float* __restrict__ lin32,
    const float* __restrict__ b_conv,
    const float* __restrict__ w_pred,
    const uint4* __restrict__ wfrag,
    float* __restrict__ out)
{
  __shared__ float xb[64 * 132];   // 33792 B fp32 staging, +4 dword row pad

  const int tid = threadIdx.x;
  const int wv = tid >> 6, lane = tid & 63;
  const int m16 = lane & 15, q2 = lane >> 4;
  const int ch0 = wv * 32 + m16;        // v=0 channel
  const int ch1 = ch0 + 16;             // v=1 channel

  const int i = blockIdx.x;
  const int ibase = i & ~63, io = i & 63;
  const int g = i >> 6;

  // 26 edge attrs (4 bits each) — function of i only
  unsigned pk[4] = {0u, 0u, 0u, 0u};
  #pragma unroll
  for (int m = 0; m < 26; ++m) {
    const int kg = ibase + ((io + OKv[m]) & 63);
    const unsigned a = (unsigned)edge_attr[(kg << 2) + DIv[m]];
    pk[m >> 3] |= a << ((m & 7) * 4);
  }

  // tupleinit directly in C-layout: X[v][mt][r], logical ps=mt&1, k=(mt>>1)*4+r
  const int xi = x[i];
  const float xe0 = emb_x[xi * EMB + ch0];
  const float xe1 = emb_x[xi * EMB + ch1];
  float lj0[2], lj1[2];
  #pragma unroll
  for (int ps = 0; ps < 2; ++ps) {
    const int jn = ibase + ((io + 2 * q2 + ps) & 63);
    const int xj = x[jn];
    lj0[ps] = lin32[xj * EMB + ch0];
    lj1[ps] = lin32[xj * EMB + ch1];
  }
  floatx4 X[2][4];
  #pragma unroll
  for (int mt = 0; mt < 4; ++mt) {
    const int ps = mt & 1, kb = (mt >> 1) * 4;
    const int t0 = (i * 8 + 2 * q2 + ps) << 3;
    #pragma unroll
    for (int r = 0; r < 4; ++r) {
      const int t = t0 + kb + r;
      const int2 tf2 = *(const int2*)(tuplefeat + 2 * t);
      const float tfa = emb_tf[((ch0 >> 6) ? tf2.y : tf2.x) * 64 + (ch0 & 63)];
      const float tfb = emb_tf[((ch1 >> 6) ? tf2.y : tf2.x) * 64 + (ch1 & 63)];
      X[0][mt][r] = xe0 * lj0[ps] * tfa;
      X[1][mt][r] = xe1 * lj1[ps] * tfb;
    }
  }

  for (int l = 0; l < 5; ++l) {
    // ---- message pass, lane-local on C-layout registers ----
    float acc[2][2][8];
    #pragma unroll
    for (int v = 0; v < 2; ++v)
      #pragma unroll
      for (int ps = 0; ps < 2; ++ps)
        #pragma unroll
        for (int k = 0; k < 8; ++k) acc[v][ps][k] = 0.f;
    #pragma unroll
    for (int m = 0; m < 26; ++m) {
      const unsigned attr = (pk[m >> 3] >> ((m & 7) * 4)) & 15u;
      const float* er = emb_ea + attr * EMB;
      const float e0 = er[ch0], e1 = er[ch1];
      const int ok = OKv[m], ol = OLv[m];
      const int mtl = 2 * (ol >> 2), rl = ol & 3;    // compile-time consts
      acc[0][0][ok] = fmaf(X[0][mtl + 0][rl], e0, acc[0][0][ok]);
      acc[0][1][ok] = fmaf(X[0][mtl + 1][rl], e0, acc[0][1][ok]);
      acc[1][0][ok] = fmaf(X[1][mtl + 0][rl], e1, acc[1][0][ok]);
      acc[1][1][ok] = fmaf(X[1][mtl + 1][rl], e1, acc[1][1][ok]);
    }
    // ---- stage acc fp32 to LDS in M-row-permuted order ----
    #pragma unroll
    for (int ps = 0; ps < 2; ++ps)
      #pragma unroll
      for (int k = 0; k < 8; ++k) {
        const int row = (ps + 2 * (k >> 2)) * 16 + q2 * 4 + (k & 3);
        xb[row * 132 + ch0] = acc[0][ps][k];
        xb[row * 132 + ch1] = acc[1][ps][k];
      }
    __syncthreads();

    // ---- MFMA: wave computes N-tiles {2wv, 2wv+1} for all 4 M-tiles ----
    floatx4 C[2][4];
    #pragma unroll
    for (int v = 0; v < 2; ++v)
      #pragma unroll
      for (int mt = 0; mt < 4; ++mt) C[v][mt] = (floatx4){0.f, 0.f, 0.f, 0.f};

    #pragma unroll
    for (int kt = 0; kt < 4; ++kt) {
      const uint4* wp0 = wfrag + ((((l * 4 + kt) * 8 + 2 * wv) * 2) << 6);
      FragU B0h, B0l, B1h, B1l;
      B0h.q = wp0[lane];        B0l.q = wp0[64 + lane];
      B1h.q = wp0[128 + lane];  B1l.q = wp0[192 + lane];
      #pragma unroll
      for (int mt = 0; mt < 4; ++mt) {
        const float* ap = xb + (mt * 16 + m16) * 132 + kt * 32 + q2 * 8;
        const float4 f0 = ld4(ap);
        const float4 f1 = ld4(ap + 4);
        FragU Ah, Al;
        const unsigned h01 = cvt_pk_bf16(f0.x, f0.y);
        const unsigned h23 = cvt_pk_bf16(f0.z, f0.w);
        const unsigned h45 = cvt_pk_bf16(f1.x, f1.y);
        const unsigned h67 = cvt_pk_bf16(f1.z, f1.w);
        Ah.u[0] = h01; Ah.u[1] = h23; Ah.u[2] = h45; Ah.u[3] = h67;
        Al.u[0] = cvt_pk_bf16(f0.x - __uint_as_float(h01 << 16),
                              f0.y - __uint_as_float(h01 & 0xFFFF0000u));
        Al.u[1] = cvt_pk_bf16(f0.z - __uint_as_float(h23 << 16),
                              f0.w - __uint_as_float(h23 & 0xFFFF0000u));
        Al.u[2] = cvt_pk_bf16(f1.x - __uint_as_float(h45 << 16),
                              f1.y - __uint_as_float(h45 & 0xFFFF0000u));
        Al.u[3] = cvt_pk_bf16(f1.z - __uint_as_float(h67 << 16),
                              f1.w - __uint_as_float(h67 & 0xFFFF0000u));
        C[0][mt] = __builtin_amdgcn_mfma_f32_16x16x32_bf16(Ah.v, B0h.v, C[0][mt], 0, 0, 0);
        C[0][mt] = __builtin_amdgcn_mfma_f32_16x16x32_bf16(Al.v, B0h.v, C[0][mt], 0, 0, 0);
        C[0][mt] = __builtin_amdgcn_mfma_f32_16x16x32_bf16(Ah.v, B0l.v, C[0][mt], 0, 0, 0);
        C[1][mt] = __builtin_amdgcn_mfma_f32_16x16x32_bf16(Ah.v, B1h.v, C[1][mt], 0, 0, 0);
        C[1][mt] = __builtin_amdgcn_mfma_f32_16x16x32_bf16(Al.v, B1h.v, C[1][mt], 0, 0, 0);
        C[1][mt] = __builtin_amdgcn_mfma_f32_16x16x32_bf16(Ah.v, B1l.v, C[1][mt], 0, 0, 0);
      }
    }
    __syncthreads();   // all reads done before next layer overwrites xb

    // ---- residual + relu, all in registers (C rows are all one channel) ----
    const float bc0 = b_conv[l * EMB + ch0];
    const float bc1 = b_conv[l * EMB + ch1];
    #pragma unroll
    for (int mt = 0; mt < 4; ++mt)
      #pragma unroll
      for (int r = 0; r < 4; ++r) {
        X[0][mt][r] += fmaxf(C[0][mt][r] + bc0, 0.f);
        X[1][mt][r] += fmaxf(C[1][mt][r] + bc1, 0.f);
      }
  }

  // ---- pooling: max over k (lane-local), sum pairs+channels via xor-reduce ----
  float s = 0.f;
  #pragma unroll
  for (int v = 0; v < 2; ++v) {
    float p0 = -3.4e38f, p1 = -3.4e38f;
    #pragma unroll
    for (int r = 0; r < 4; ++r) {
      p0 = fmaxf(p0, fmaxf(X[v][0][r], X[v][2][r]));   // ps=0: mt 0,2
      p1 = fmaxf(p1, fmaxf(X[v][1][r], X[v][3][r]));   // ps=1: mt 1,3
    }
    const float wp = w_pred[v ? ch1 : ch0];
    s = fmaf(p0 + p1, wp, s);
  }
  #pragma unroll
  for (int off = 32; off; off >>= 1) s += __shfl_xor(s, off, 64);
  if (lane == 0) atomicAdd(out + g, s);
}

extern "C" void kernel_launch(void* const* d_in, const int* in_sizes, int n_in,
                              void* d_out, int out_size, void* d_ws, size_t ws_size,
                              hipStream_t stream) {
  const int*   x         = (const int*)d_in[0];
  const int*   edge_attr = (const int*)d_in[1];
  const int*   tuplefeat = (const int*)d_in[2];
  const float* emb_x     = (const float*)d_in[12];
  const float* emb_ea    = (const float*)d_in[13];
  const float* emb_tf    = (const float*)d_in[14];
  const float* w_ti      = (const float*)d_in[15];
  const float* b_ti      = (const float*)d_in[16];
  const float* w_conv    = (const float*)d_in[17];
  const float* b_conv    = (const float*)d_in[18];
  const float* w_pred    = (const float*)d_in[19];
  const float* b_pred    = (const float*)d_in[20];
  float* out = (float*)d_out;
  float* lin32 = (float*)d_ws;                               // 32*128 fp32 = 16 KB
  uint4* wfrag = (uint4*)((char*)d_ws + 32 * EMB * 4);       // 320 KB B-fragments

  hipLaunchKernelGGL(prep_kernel, dim3(112), dim3(256), 0, stream,
                     emb_x, w_ti, b_ti, w_conv, b_pred, lin32, wfrag, out);
  hipLaunchKernelGGL(i2gnn_mfma, dim3(4096), dim3(256), 0, stream,
                     x, edge_attr, tuplefeat, emb_x, emb_tf, emb_ea, lin32,
                     b_conv, w_pred, wfrag, out);
}

// Round 9
// 300.459 us; speedup vs baseline: 1.1114x; 1.1114x over previous
//
#include <hip/hip_runtime.h>
#include <hip/hip_bf16.h>

#define EMB 128

typedef __attribute__((ext_vector_type(8))) short short8;   // 8 bf16 (4 VGPRs)
typedef __attribute__((ext_vector_type(4))) float floatx4;  // MFMA C/D

// 26 valid (ok, di, ol) message combos: deltas = {1,2,-1,-2}, ol = ok+delta in [0,8)
static constexpr int OKv[26] = {0,0,1,1,1,2,2,2,2,3,3,3,3,4,4,4,4,5,5,5,5,6,6,6,7,7};
static constexpr int DIv[26] = {0,1,0,1,2,0,1,2,3,0,1,2,3,0,1,2,3,0,1,2,3,0,2,3,2,3};
static constexpr int OLv[26] = {1,2,2,3,0,3,4,1,0,4,5,2,1,5,6,3,2,6,7,4,3,7,5,4,6,5};

__device__ __forceinline__ float2 ld2(const float* p) { return *(const float2*)p; }

// round-to-nearest-even bf16 bits of x, kept in the TOP 16 bits (low 16 zero)
__device__ __forceinline__ unsigned bf16_rne_hi(float x) {
  unsigned u = __float_as_uint(x);
  return (u + 0x7FFFu + ((u >> 16) & 1u)) & 0xFFFF0000u;
}
__device__ __forceinline__ float bf16hi_f(float x) {
  return __uint_as_float(bf16_rne_hi(x));
}
// HW packed cvt: a -> low 16, b -> high 16 (v_cvt_pk_bf16_f32 on gfx950)
__device__ __forceinline__ unsigned cvt_pk_bf16(float a, float b) {
  __hip_bfloat162 h = __float22bfloat162_rn(make_float2(a, b));
  unsigned r; __builtin_memcpy(&r, &h, 4); return r;
}

union FragU { unsigned u[4]; uint4 q; short8 v; };

// LOGICAL CHANNEL PERMUTATION: MFMA C physical position (u, n=lane&15) carries
// logical (canonical) channel  L(u,n) = 2*((u>>1)*16 + n) + (u&1).
// Wave wv computes u in {2wv, 2wv+1} -> lane (wv, m16) holds the ADJACENT
// logical pair c0 = 2*(wv*16+m16), c0+1. All channel-indexed tensors
// (emb_ea, b_conv, w_pred, emb_x, emb_tf, lin32) are read at logical indices;
// only wfrag bakes the permutation (B column (u,n) = w_conv[.][kk][L(u,n)]).

// Fused prep: blocks 0..31 = lin32 rows (+ block 0 writes out[g]=b_pred),
// blocks 32..111 = w_conv -> B-fragment hi/lo pre-pack with permuted N.
__global__ void prep_kernel(const float* __restrict__ emb_x,
                            const float* __restrict__ w_ti,
                            const float* __restrict__ b_ti,
                            const float* __restrict__ w_conv,
                            const float* __restrict__ b_pred,
                            float* __restrict__ lin32,
                            uint4* __restrict__ wfrag,
                            float* __restrict__ out) {
  const int b = blockIdx.x, tid = threadIdx.x;
  if (b < 32) {
    if (tid < EMB) {
      const int e = tid;
      const float* xr = emb_x + b * EMB;
      float a0 = b_ti[e], a1 = 0.f, a2 = 0.f, a3 = 0.f;
      #pragma unroll 4
      for (int f = 0; f < EMB; f += 4) {
        a0 = fmaf(xr[f + 0], w_ti[(f + 0) * EMB + e], a0);
        a1 = fmaf(xr[f + 1], w_ti[(f + 1) * EMB + e], a1);
        a2 = fmaf(xr[f + 2], w_ti[(f + 2) * EMB + e], a2);
        a3 = fmaf(xr[f + 3], w_ti[(f + 3) * EMB + e], a3);
      }
      lin32[b * EMB + e] = (a0 + a1) + (a2 + a3);
    } else if (b == 0 && tid >= 128 && tid < 192) {
      out[tid - 128] = b_pred[0];
    }
  } else {
    const int id   = (b - 32) * 256 + tid;   // 320 frags * 64 lanes = 20480
    const int lane = id & 63;
    const int f    = id >> 6;
    const int pass = f & 1;           // 0 = hi, 1 = lo
    const int u    = (f >> 1) & 7;    // N-tile (physical)
    const int t    = (f >> 4) & 3;    // K-tile
    const int l    = f >> 6;          // layer
    const int q    = lane >> 4, n = lane & 15;
    const int cN   = 2 * ((u >> 1) * 16 + n) + (u & 1);   // logical out channel
    unsigned w[4] = {0u, 0u, 0u, 0u};
    #pragma unroll
    for (int j = 0; j < 8; ++j) {
      const int kk = t * 32 + q * 8 + j;    // logical in channel
      float val = w_conv[l * (EMB * EMB) + kk * EMB + cN];
      if (pass) val = val - bf16hi_f(val);
      const unsigned bb = bf16_rne_hi(val);
      w[j >> 1] |= (j & 1) ? bb : (bb >> 16);
    }
    wfrag[id] = make_uint4(w[0], w[1], w[2], w[3]);
  }
}

// Block = root node i. X stays in MFMA C-layout registers all 5 layers
// (M-row perm row(pair,k) = ((pair&1)+2*(k>>2))*16 + (pair>>1)*4 + (k&3)).
// Per layer: lane-local fp32 message pass (float2 ea from global/L1) ->
// single producer-side hi/lo bf16 pack written as uint32 DIRECTLY into the
// A-fragment LDS buffer (stride-68 rows: b32 writes 2-way free, b128 reads
// at the 8-sweep data floor) -> MFMA (2 N-tiles x 4 M-tiles x 4 kt x 3
// split-terms) -> residual+relu in registers. 2 barriers/layer, no epilogue
// round-trip, no redundant cvt. No occupancy attribute (R1/R6: forcing a
// budget makes the allocator spill ~0.5-1.6 GB).
__global__ __launch_bounds__(256)
void i2gnn_mfma(
    const int* __restrict__ x,
    const int* __restrict__ edge_attr,
    const int* __restrict__ tuplefeat,
    const float* __restrict__ emb_x,
    const float* __restrict__ emb_tf,
    const float* __restrict__ emb_ea,
    const float* __restrict__ lin32,
    const float* __restrict__ b_conv,
    const float* __restrict__ w_pred,
    const uint4* __restrict__ wfrag,
    float* __restrict__ out)
{
  __shared__ __align__(16) unsigned fragA[2 * 64 * 68];   // 34816 B, lo at +4352

  const int tid = threadIdx.x;
  const int wv = tid >> 6, lane = tid & 63;
  const int m16 = lane & 15, q2 = lane >> 4;
  const int pc = wv * 16 + m16;        // logical pair-column this lane produces
  const int c0 = pc * 2;               // logical channels c0, c0+1

  const int i = blockIdx.x;
  const int ibase = i & ~63, io = i & 63;
  const int g = i >> 6;

  // 26 edge attrs (4 bits each) — function of i only
  unsigned pk[4] = {0u, 0u, 0u, 0u};
  #pragma unroll
  for (int m = 0; m < 26; ++m) {
    const int kg = ibase + ((io + OKv[m]) & 63);
    const unsigned a = (unsigned)edge_attr[(kg << 2) + DIv[m]];
    pk[m >> 3] |= a << ((m & 7) * 4);
  }

  // tupleinit in C-layout: X[v][mt][r]; pair ps = mt&1 (this lane: 2*q2+ps),
  // k = (mt>>1)*4 + r; channels c0+v (adjacent logical pair).
  const int xi = x[i];
  const float2 xe = ld2(emb_x + xi * EMB + c0);
  float2 lj[2];
  #pragma unroll
  for (int ps = 0; ps < 2; ++ps) {
    const int jn = ibase + ((io + 2 * q2 + ps) & 63);
    lj[ps] = ld2(lin32 + x[jn] * EMB + c0);
  }
  floatx4 X[2][4];
  #pragma unroll
  for (int mt = 0; mt < 4; ++mt) {
    const int ps = mt & 1, kb = (mt >> 1) * 4;
    const int t0 = (i * 8 + 2 * q2 + ps) << 3;
    #pragma unroll
    for (int r = 0; r < 4; ++r) {
      const int2 tf2 = *(const int2*)(tuplefeat + 2 * (t0 + kb + r));
      const int row = (c0 < 64) ? tf2.x : tf2.y;   // c0,c0+1 in same half
      const float2 tf = ld2(emb_tf + row * 64 + (c0 & 63));
      X[0][mt][r] = xe.x * lj[ps].x * tf.x;
      X[1][mt][r] = xe.y * lj[ps].y * tf.y;
    }
  }

  for (int l = 0; l < 5; ++l) {
    // ---- message pass, lane-local on logical channels c0, c0+1 ----
    float acc[2][2][8];   // [v][ps][k]
    #pragma unroll
    for (int v = 0; v < 2; ++v)
      #pragma unroll
      for (int ps = 0; ps < 2; ++ps)
        #pragma unroll
        for (int k = 0; k < 8; ++k) acc[v][ps][k] = 0.f;
    #pragma unroll
    for (int m = 0; m < 26; ++m) {
      const unsigned attr = (pk[m >> 3] >> ((m & 7) * 4)) & 15u;
      const float2 e = ld2(emb_ea + attr * EMB + c0);
      const int ok = OKv[m], ol = OLv[m];
      const int mtb = 2 * (ol >> 2), rl = ol & 3;   // compile-time consts
      acc[0][0][ok] = fmaf(X[0][mtb + 0][rl], e.x, acc[0][0][ok]);
      acc[0][1][ok] = fmaf(X[0][mtb + 1][rl], e.x, acc[0][1][ok]);
      acc[1][0][ok] = fmaf(X[1][mtb + 0][rl], e.y, acc[1][0][ok]);
      acc[1][1][ok] = fmaf(X[1][mtb + 1][rl], e.y, acc[1][1][ok]);
    }
    // ---- single hi/lo pack, written straight into A-fragment layout ----
    #pragma unroll
    for (int ps = 0; ps < 2; ++ps)
      #pragma unroll
      for (int k = 0; k < 8; ++k) {
        const float a0 = acc[0][ps][k], a1 = acc[1][ps][k];
        const unsigned hi = cvt_pk_bf16(a0, a1);
        const float r0 = a0 - __uint_as_float(hi << 16);
        const float r1 = a1 - __uint_as_float(hi & 0xFFFF0000u);
        const int row = (ps + 2 * (k >> 2)) * 16 + q2 * 4 + (k & 3);
        fragA[row * 68 + pc] = hi;
        fragA[4352 + row * 68 + pc] = cvt_pk_bf16(r0, r1);
      }
    __syncthreads();

    // ---- MFMA: wave computes N-tiles {2wv, 2wv+1} for all 4 M-tiles ----
    floatx4 C[2][4];
    #pragma unroll
    for (int v = 0; v < 2; ++v)
      #pragma unroll
      for (int mt = 0; mt < 4; ++mt) C[v][mt] = (floatx4){0.f, 0.f, 0.f, 0.f};

    #pragma unroll
    for (int kt = 0; kt < 4; ++kt) {
      const uint4* wp0 = wfrag + ((((l * 4 + kt) * 8 + 2 * wv) * 2) << 6);
      FragU B0h, B0l, B1h, B1l;
      B0h.q = wp0[lane];        B0l.q = wp0[64 + lane];
      B1h.q = wp0[128 + lane];  B1l.q = wp0[192 + lane];
      #pragma unroll
      for (int mt = 0; mt < 4; ++mt) {
        const unsigned* fa = fragA + (mt * 16 + m16) * 68 + kt * 16 + q2 * 4;
        FragU Ah, Al;
        Ah.q = *(const uint4*)fa;
        Al.q = *(const uint4*)(fa + 4352);
        C[0][mt] = __builtin_amdgcn_mfma_f32_16x16x32_bf16(Ah.v, B0h.v, C[0][mt], 0, 0, 0);
        C[0][mt] = __builtin_amdgcn_mfma_f32_16x16x32_bf16(Al.v, B0h.v, C[0][mt], 0, 0, 0);
        C[0][mt] = __builtin_amdgcn_mfma_f32_16x16x32_bf16(Ah.v, B0l.v, C[0][mt], 0, 0, 0);
        C[1][mt] = __builtin_amdgcn_mfma_f32_16x16x32_bf16(Ah.v, B1h.v, C[1][mt], 0, 0, 0);
        C[1][mt] = __builtin_amdgcn_mfma_f32_16x16x32_bf16(Al.v, B1h.v, C[1][mt], 0, 0, 0);
        C[1][mt] = __builtin_amdgcn_mfma_f32_16x16x32_bf16(Ah.v, B1l.v, C[1][mt], 0, 0, 0);
      }
    }
    __syncthreads();   // reads done before next layer overwrites fragA

    // ---- residual + relu in registers (lane's C entries are c0, c0+1) ----
    const float2 bc = ld2(b_conv + l * EMB + c0);
    #pragma unroll
    for (int mt = 0; mt < 4; ++mt)
      #pragma unroll
      for (int r = 0; r < 4; ++r) {
        X[0][mt][r] += fmaxf(C[0][mt][r] + bc.x, 0.f);
        X[1][mt][r] += fmaxf(C[1][mt][r] + bc.y, 0.f);
      }
  }

  // ---- pooling: max over k per (v, pair), dot w_pred, xor-reduce, atomic ----
  const float2 wp = ld2(w_pred + c0);
  float s = 0.f;
  #pragma unroll
  for (int v = 0; v < 2; ++v) {
    float p0 = -3.4e38f, p1 = -3.4e38f;
    #pragma unroll
    for (int r = 0; r < 4; ++r) {
      p0 = fmaxf(p0, fmaxf(X[v][0][r], X[v][2][r]));   // ps=0: mt 0,2
      p1 = fmaxf(p1, fmaxf(X[v][1][r], X[v][3][r]));   // ps=1: mt 1,3
    }
    s = fmaf(p0 + p1, v ? wp.y : wp.x, s);
  }
  #pragma unroll
  for (int off = 32; off; off >>= 1) s += __shfl_xor(s, off, 64);
  if (lane == 0) atomicAdd(out + g, s);
}

extern "C" void kernel_launch(void* const* d_in, const int* in_sizes, int n_in,
                              void* d_out, int out_size, void* d_ws, size_t ws_size,
                              hipStream_t stream) {
  const int*   x         = (const int*)d_in[0];
  const int*   edge_attr = (const int*)d_in[1];
  const int*   tuplefeat = (const int*)d_in[2];
  const float* emb_x     = (const float*)d_in[12];
  const float* emb_ea    = (const float*)d_in[13];
  const float* emb_tf    = (const float*)d_in[14];
  const float* w_ti      = (const float*)d_in[15];
  const float* b_ti      = (const float*)d_in[16];
  const float* w_conv    = (const float*)d_in[17];
  const float* b_conv    = (const float*)d_in[18];
  const float* w_pred    = (const float*)d_in[19];
  const float* b_pred    = (const float*)d_in[20];
  float* out = (float*)d_out;
  float* lin32 = (float*)d_ws;                               // 32*128 fp32 = 16 KB
  uint4* wfrag = (uint4*)((char*)d_ws + 32 * EMB * 4);       // 320 KB B-fragments

  hipLaunchKernelGGL(prep_kernel, dim3(112), dim3(256), 0, stream,
                     emb_x, w_ti, b_ti, w_conv, b_pred, lin32, wfrag, out);
  hipLaunchKernelGGL(i2gnn_mfma, dim3(4096), dim3(256), 0, stream,
                     x, edge_attr, tuplefeat, emb_x, emb_tf, emb_ea, lin32,
                     b_conv, w_pred, wfrag, out);
}